// Round 5
// baseline (427.395 us; speedup 1.0000x reference)
//
#include <hip/hip_runtime.h>
#include <hip/hip_bf16.h>
#include <math.h>

#define DIM   2048
#define NH    16
#define HD    128
#define SEQ   2048
#define BATCH 2
#define QKVN  6144   // 3*DIM

typedef __attribute__((ext_vector_type(8))) short short8;
typedef __attribute__((ext_vector_type(4))) float f32x4;
typedef __attribute__((ext_vector_type(4))) unsigned int u32x4;
typedef __attribute__((ext_vector_type(4))) _Float16 half4;

static __device__ __forceinline__ unsigned short f2bf(float f) {
    __hip_bfloat16 h = __float2bfloat16(f);
    return *reinterpret_cast<unsigned short*>(&h);
}

// async global->LDS, 16B per lane; LDS dest = base + lane*16 (wave-uniform base)
static __device__ __forceinline__ void gload16(const void* g, void* l) {
    __builtin_amdgcn_global_load_lds(
        (const __attribute__((address_space(1))) void*)(g),
        (__attribute__((address_space(3))) void*)(l), 16, 0, 0);
}

__device__ __forceinline__ void storeC_helper(float* C, size_t idx, float v) { C[idx] = v; }
__device__ __forceinline__ void storeC_helper(__hip_bfloat16* C, size_t idx, float v) { C[idx] = __float2bfloat16(v); }

// ---- scheduling primitives (raw barriers, counted waits) ----
#define GFENCE()  asm volatile("" ::: "memory")
#define GBAR()    do { GFENCE(); __builtin_amdgcn_s_barrier(); GFENCE(); } while (0)
// rule #18: sched_barrier(0) after inline-asm lgkmcnt so MFMAs can't hoist above it
#define GWAITL0() do { asm volatile("s_waitcnt lgkmcnt(0)" ::: "memory"); __builtin_amdgcn_sched_barrier(0); } while (0)
#define GWAITV(n) asm volatile("s_waitcnt vmcnt(" n ")" ::: "memory")

// ---------------- fused cast fp32 -> bf16 (x + 4 weights, one launch) ----------------
__global__ __launch_bounds__(256) void cast_all(const float* __restrict__ x,
                                                const float* __restrict__ wq,
                                                const float* __restrict__ wk,
                                                const float* __restrict__ wv,
                                                const float* __restrict__ wo,
                                                __hip_bfloat16* __restrict__ xb,
                                                __hip_bfloat16* __restrict__ wqkvb,
                                                __hip_bfloat16* __restrict__ wob) {
    const int VX = (BATCH * SEQ * DIM) / 4;
    const int VW = (DIM * DIM) / 4;
    int v = blockIdx.x * blockDim.x + threadIdx.x;
    const float* src; __hip_bfloat16* dst; int off;
    if (v < VX)               { src = x;  dst = xb;                            off = v; }
    else if (v < VX + VW)     { src = wq; dst = wqkvb;                         off = v - VX; }
    else if (v < VX + 2 * VW) { src = wk; dst = wqkvb + (size_t)DIM * DIM;     off = v - VX - VW; }
    else if (v < VX + 3 * VW) { src = wv; dst = wqkvb + 2ull * DIM * DIM;      off = v - VX - 2 * VW; }
    else                      { src = wo; dst = wob;                           off = v - VX - 3 * VW; }
    float4 f = *(const float4*)(src + (size_t)off * 4);
    union { unsigned short u[4]; uint2 d; } pk;
    pk.u[0] = f2bf(f.x); pk.u[1] = f2bf(f.y); pk.u[2] = f2bf(f.z); pk.u[3] = f2bf(f.w);
    *(uint2*)(dst + (size_t)off * 4) = pk.d;
}

// ---------------- 256x256 bf16 GEMM, BK=32, 4-deep LDS ring (QKV fused) ----------
// C[m,n] = sum_k A[m,k]*B[n,k], M=4096, N=6144, K=2048. 512 thr = 8 waves (2Mx4N),
// per-wave out 128x64 (acc[8][4] in AGPRs). 64 K-tiles of 32; 2 phases/tile:
//   P1: read B(4 b128)+A-half0(4), 16 MFMA acc[0..3]
//   P2: read A-half1(4),          16 MFMA acc[4..7]
// Live frags = 8 short8 = 32 VGPR (no spill at 2 waves/SIMD).
// Ring: buf = T&3 (4 x 32KB = 128KB). Stage tile T+3 during T (P1: A rows, P2: B
// rows; 1 gload16/thread per round). WAR-safe: buf(T+3)=buf(T-1), drained at
// P2(T-1) end-barrier. Gate T+1 at P2(T): vmcnt(8) counted (T+2,T+3 younger;
// FIFO retires T+1) -- 4-phase issue-to-wait lead, NEVER 0 mid-loop.
// Tail: vmcnt 4 @T=61, 0 @T=62. Bank swizzle: chunk ^= (row>>1)&3 (2-way = free).
template <int MOFF>
static __device__ __forceinline__ void mfma16(const short8 (&af)[4], const short8 (&bf)[4],
                                              f32x4 (&acc)[8][4]) {
    __builtin_amdgcn_s_setprio(1);
#pragma unroll
    for (int mt = 0; mt < 4; mt++)
#pragma unroll
        for (int nt = 0; nt < 4; nt++)
            acc[MOFF + mt][nt] = __builtin_amdgcn_mfma_f32_16x16x32_bf16(
                af[mt], bf[nt], acc[MOFF + mt][nt], 0, 0, 0);
    __builtin_amdgcn_s_setprio(0);
}

__global__ __attribute__((amdgpu_waves_per_eu(2, 2))) __launch_bounds__(512)
void gemm256_qkv(const __hip_bfloat16* __restrict__ A,
                 const __hip_bfloat16* __restrict__ B,
                 __hip_bfloat16* __restrict__ C,
                 _Float16* __restrict__ vt) {
    constexpr int K  = DIM;       // 2048
    constexpr int N  = QKVN;      // 6144
    constexpr int NT = K / 32;    // 64 K-tiles
    __shared__ __align__(16) __hip_bfloat16 As4[4][256 * 32];   // 64KB
    __shared__ __align__(16) __hip_bfloat16 Bs4[4][256 * 32];   // 64KB

    int tid  = threadIdx.x;
    int lane = tid & 63;
    int wave = tid >> 6;
    int wm   = wave >> 2;      // 0..1  (M half)
    int wn   = wave & 3;       // 0..3  (N quarter)
    int quad = lane >> 4;
    int l15  = lane & 15;
    int m0   = blockIdx.y * 256;
    int n0   = blockIdx.x * 256;

    f32x4 acc[8][4] = {};

    // stage round j of K-tile tau: j=0,1 -> A rows (j&1)*128..; j=2,3 -> B rows.
    // 1 gload16/thread: thread t -> local row t>>2 (0..127), chunk t&3; source
    // col-chunk pre-swizzled by (row>>1)&3 so reads use chunk = quad ^ ((row>>1)&3).
    auto stage32 = [&](int tau, int j) {
        int rl = tid >> 2;                              // 0..127
        int ch = (tid & 3) ^ ((rl >> 1) & 3);
        int rowbase = (j & 1) * 128;
        if (j < 2) {
            gload16(A + (size_t)(m0 + rowbase + rl) * K + tau * 32 + ch * 8,
                    &As4[tau & 3][(rowbase + wave * 16) * 32]);
        } else {
            gload16(B + (size_t)(n0 + rowbase + rl) * K + tau * 32 + ch * 8,
                    &Bs4[tau & 3][(rowbase + wave * 16) * 32]);
        }
    };

    // per-thread fragment offsets (row base multiple of 16 -> (row>>1)&3 = (l15>>1)&3)
    int chv  = (quad ^ ((l15 >> 1) & 3)) * 8;
    int aoff = (wm * 128 + l15) * 32 + chv;
    int boff = (wn * 64 + l15) * 32 + chv;

    // ---- prologue: stage tiles 0,1,2 (12 rounds); gate tile0 (vmcnt 8 = keep 1,2)
    for (int t = 0; t < 3; t++)
        for (int j = 0; j < 4; j++) stage32(t, j);
    GWAITV("8");
    GBAR();

    short8 fA[4], fB[4];

#pragma unroll 1
    for (int T = 0; T < NT; T++) {
        const __hip_bfloat16* ab = &As4[T & 3][0];
        const __hip_bfloat16* bb = &Bs4[T & 3][0];
        // ---- P1: stage (T+3) A; read B + A-half0; MFMA acc[0..3]
        if (T < NT - 3) { stage32(T + 3, 0); stage32(T + 3, 1); }
#pragma unroll
        for (int t = 0; t < 4; t++) fB[t] = *(const short8*)(bb + boff + t * 512);
#pragma unroll
        for (int t = 0; t < 4; t++) fA[t] = *(const short8*)(ab + aoff + t * 512);
        GBAR(); GWAITL0();
        mfma16<0>(fA, fB, acc);
        GBAR();
        // ---- P2: stage (T+3) B; read A-half1; MFMA acc[4..7]; gate T+1 (counted)
        if (T < NT - 3) { stage32(T + 3, 2); stage32(T + 3, 3); }
#pragma unroll
        for (int t = 0; t < 4; t++) fA[t] = *(const short8*)(ab + aoff + (4 + t) * 512);
        GBAR(); GWAITL0();
        mfma16<4>(fA, fB, acc);
        if (T < NT - 3)      { GWAITV("8"); }
        else if (T == NT - 3) { GWAITV("4"); }
        else if (T == NT - 2) { GWAITV("0"); }
        GBAR();
    }

    // ---------------- epilogue (block-uniform branch: n0 aligned to 256) ----------------
    int ncol0 = n0 + wn * 64;
    if (ncol0 >= 4096) {
        // V: transpose per-wave 128(s) x 64(d) via private 16KB LDS region, store f16
        _Float16* T = ((wave < 4) ? (_Float16*)As4 : (_Float16*)Bs4) + (wave & 3) * 8192;
#pragma unroll
        for (int mt = 0; mt < 8; mt++)
#pragma unroll
            for (int nt = 0; nt < 4; nt++) {
                half4 hv;
#pragma unroll
                for (int r = 0; r < 4; r++) hv[r] = (_Float16)acc[mt][nt][r];
                int chunk = mt * 2 + (quad >> 1);       // s>>3
                int phys  = chunk ^ l15;                // ^ (d&15), d = nt*16+l15
                *(half4*)(T + (nt * 16 + l15) * 128 + phys * 8 + (quad & 1) * 4) = hv;
            }
        int h  = (ncol0 - 4096) >> 7;
        int d0 = (ncol0 - 4096) & 127;                  // 0 or 64
        int b  = (m0 + wm * 128) >> 11;
        int sb = (m0 + wm * 128) & (SEQ - 1);
#pragma unroll
        for (int pass = 0; pass < 16; pass++) {
            int d = pass * 4 + quad;
            int phys = l15 ^ (d & 15);
            u32x4 val = *(const u32x4*)(T + d * 128 + phys * 8);
            *(u32x4*)(vt + ((size_t)((b * NH + h) * HD + d0 + d)) * SEQ + sb + l15 * 8) = val;
        }
    } else {
        // Q,K: fused RoPE + bf16 store
#pragma unroll
        for (int nt = 0; nt < 4; nt++) {
            int col = ncol0 + nt * 16 + l15;
            float theta = __expf(-((float)((col & 127) & ~1) * (1.0f / (float)HD)) * 9.210340371976184f);
#pragma unroll
            for (int mt = 0; mt < 8; mt++)
#pragma unroll
                for (int r = 0; r < 4; r++) {
                    int row = m0 + wm * 128 + mt * 16 + quad * 4 + r;
                    float val = acc[mt][nt][r];
                    float part = __shfl_xor(val, 1);
                    int s = row & (SEQ - 1);
                    float sn, cs;
                    __sincosf((float)s * theta, &sn, &cs);
                    val = (l15 & 1) ? val * cs + part * sn : val * cs - part * sn;
                    C[(size_t)row * N + col] = __float2bfloat16(val);
                }
        }
    }
}

// ---------------- bf16 GEMM, C[m,n] = sum_k A[m,k]*B[n,k] (128x128, out-proj) --------
template <int MODE, typename OutT>
__global__ __launch_bounds__(256) void gemm_bt(const __hip_bfloat16* __restrict__ A,
                                               const __hip_bfloat16* __restrict__ B,
                                               OutT* __restrict__ C,
                                               _Float16* __restrict__ vt,
                                               int M, int N, int K) {
    constexpr int BK = 64;
    __shared__ __align__(16) __hip_bfloat16 As[128 * BK];
    __shared__ __align__(16) __hip_bfloat16 Bs[128 * BK];
    int tid  = threadIdx.x;
    int lane = tid & 63;
    int wave = tid >> 6;
    int quad = lane >> 4;
    int l15  = lane & 15;
    int wr   = wave >> 1, wc = wave & 1;
    int m0 = blockIdx.y * 128;
    int n0 = blockIdx.x * 128;
    f32x4 acc[4][4] = {};

    for (int k0 = 0; k0 < K; k0 += BK) {
        __syncthreads();
#pragma unroll
        for (int c = 0; c < 4; c++) {
            int br = (wave * 4 + c) * 8;
            int r  = br + (lane >> 3);
            int cc = (lane & 7) ^ (r & 7);
            gload16(A + (size_t)(m0 + r) * K + k0 + cc * 8, As + br * 64);
            gload16(B + (size_t)(n0 + r) * K + k0 + cc * 8, Bs + br * 64);
        }
        __syncthreads();
#pragma unroll
        for (int kk = 0; kk < BK; kk += 32) {
            short8 af[4], bf4[4];
#pragma unroll
            for (int t = 0; t < 4; t++) {
                int Ra = wr * 64 + t * 16 + l15;
                int pa = ((kk >> 3) + quad) ^ (Ra & 7);
                af[t] = *(const short8*)(As + Ra * 64 + pa * 8);
                int Rb = wc * 64 + t * 16 + l15;
                int pb = ((kk >> 3) + quad) ^ (Rb & 7);
                bf4[t] = *(const short8*)(Bs + Rb * 64 + pb * 8);
            }
#pragma unroll
            for (int mt = 0; mt < 4; mt++)
#pragma unroll
                for (int nt = 0; nt < 4; nt++)
                    acc[mt][nt] = __builtin_amdgcn_mfma_f32_16x16x32_bf16(af[mt], bf4[nt], acc[mt][nt], 0, 0, 0);
        }
    }

#pragma unroll
    for (int nt = 0; nt < 4; nt++) {
        int col = n0 + wc * 64 + nt * 16 + l15;
#pragma unroll
        for (int mt = 0; mt < 4; mt++)
#pragma unroll
            for (int r = 0; r < 4; r++) {
                int row = m0 + wr * 64 + mt * 16 + quad * 4 + r;
                storeC_helper(C, (size_t)row * N + col, acc[mt][nt][r]);
            }
    }
}

// ---------------- flash attention (causal) ----------------
// 512 threads = 8 waves = 2 groups x 4. qtile=128 (wave owns 32 q-rows).
// Group g processes half the key range; online-softmax partials merged in LDS.
// Pairs (i,15-i): every block 17+17 iters. grid (8,32)=256 blocks, 2 waves/SIMD.
// S^T = K·Q^T so P exits in B-operand layout for 16x16x16 f16 PV.
__global__ __launch_bounds__(512, 2) void flash_kernel(const __hip_bfloat16* __restrict__ qkv,
                                                       const _Float16* __restrict__ vt,
                                                       __hip_bfloat16* __restrict__ attn) {
    __shared__ __align__(16) __hip_bfloat16 Ks[2][2][64 * 128];   // [group][buf] 64KB
    __shared__ __align__(16) _Float16 Vts[2][2][128 * 64];        // [group][buf] 64KB
    int tid  = threadIdx.x;
    int lane = tid & 63;
    int wave = tid >> 6;
    int grp  = wave >> 2;
    int wl   = wave & 3;
    int quad = lane >> 4;
    int l15  = lane & 15;
    int pairi = blockIdx.x;
    int bh = blockIdx.y;
    int b  = bh >> 4;
    int h  = bh & 15;
    size_t row0 = (size_t)b * SEQ;
    const _Float16* vbase = vt + (size_t)bh * HD * SEQ;
    const float scale = 0.08838834764831845f;
    const float NEG = -1e30f;

    auto stage = [&](int buf, int kt) {
#pragma unroll
        for (int c = 0; c < 4; c++) {
            int br = (wl * 4 + c) * 4;
            int r  = br + (lane >> 4);
            int cc = (lane & 15) ^ (r & 15);
            gload16(qkv + (row0 + kt * 64 + r) * (size_t)QKVN + DIM + h * HD + cc * 8,
                    &Ks[grp][buf][br * 128]);
        }
#pragma unroll
        for (int c = 0; c < 4; c++) {
            int br = (wl * 4 + c) * 8;
            int r  = br + (lane >> 3);
            int cc = (lane & 7) ^ ((r >> 1) & 7);
            gload16(vbase + (size_t)r * SEQ + kt * 64 + cc * 8, &Vts[grp][buf][br * 64]);
        }
    };

    for (int seg = 0; seg < 2; seg++) {
        int qt = seg ? (15 - pairi) : pairi;
        int half = qt + 1;
        int kbase = grp ? half : 0;

        short8 qf[2][4];
#pragma unroll
        for (int mt = 0; mt < 2; mt++) {
            int qrow = qt * 128 + wl * 32 + mt * 16 + l15;
            const __hip_bfloat16* qptr = qkv + (row0 + qrow) * (size_t)QKVN + h * HD + quad * 8;
#pragma unroll
            for (int c = 0; c < 4; c++) qf[mt][c] = *(const short8*)(qptr + c * 32);
        }
        f32x4 o[2][8] = {};
        float m_[2] = {NEG, NEG}, l_[2] = {0.f, 0.f};

        stage(0, kbase);

        for (int i = 0; i < half; i++) {
            __syncthreads();
            if (i + 1 < half) stage((i + 1) & 1, kbase + i + 1);
            int kt = kbase + i;
            const __hip_bfloat16* ks = Ks[grp][i & 1];
            const _Float16* vts = Vts[grp][i & 1];

            f32x4 s[2][4] = {};
#pragma unroll
            for (int ktile = 0; ktile < 4; ktile++) {
                int R = ktile * 16 + l15;
#pragma unroll
                for (int c = 0; c < 4; c++) {
                    int phys = (c * 4 + quad) ^ (R & 15);
                    short8 kf = *(const short8*)(ks + R * 128 + phys * 8);
                    s[0][ktile] = __builtin_amdgcn_mfma_f32_16x16x32_bf16(kf, qf[0][c], s[0][ktile], 0, 0, 0);
                    s[1][ktile] = __builtin_amdgcn_mfma_f32_16x16x32_bf16(kf, qf[1][c], s[1][ktile], 0, 0, 0);
                }
            }
            bool diag = (kt >= 2 * qt);
            float alpha[2];
#pragma unroll
            for (int mt = 0; mt < 2; mt++) {
                int q = qt * 128 + wl * 32 + mt * 16 + l15;
#pragma unroll
                for (int ktile = 0; ktile < 4; ktile++)
#pragma unroll
                    for (int r = 0; r < 4; r++) {
                        float v = s[mt][ktile][r] * scale;
                        if (diag) {
                            int key = kt * 64 + ktile * 16 + quad * 4 + r;
                            if (key > q) v = NEG;
                        }
                        s[mt][ktile][r] = v;
                    }
                float v = s[mt][0][0];
#pragma unroll
                for (int ktile = 0; ktile < 4; ktile++)
#pragma unroll
                    for (int r = 0; r < 4; r++) v = fmaxf(v, s[mt][ktile][r]);
                v = fmaxf(v, __shfl_xor(v, 16));
                v = fmaxf(v, __shfl_xor(v, 32));
                float mnew = fmaxf(m_[mt], v);
                alpha[mt] = __expf(m_[mt] - mnew);
                m_[mt] = mnew;
                float sum = 0.f;
#pragma unroll
                for (int ktile = 0; ktile < 4; ktile++)
#pragma unroll
                    for (int r = 0; r < 4; r++) {
                        float p = __expf(s[mt][ktile][r] - mnew);
                        s[mt][ktile][r] = p;
                        sum += p;
                    }
                sum += __shfl_xor(sum, 16);
                sum += __shfl_xor(sum, 32);
                l_[mt] = l_[mt] * alpha[mt] + sum;
#pragma unroll
                for (int dt = 0; dt < 8; dt++) o[mt][dt] *= alpha[mt];
            }
            half4 pk[2][4];
#pragma unroll
            for (int mt = 0; mt < 2; mt++)
#pragma unroll
                for (int kc = 0; kc < 4; kc++)
#pragma unroll
                    for (int r = 0; r < 4; r++) pk[mt][kc][r] = (_Float16)s[mt][kc][r];
#pragma unroll
            for (int kc = 0; kc < 4; kc++)
#pragma unroll
                for (int dt = 0; dt < 8; dt++) {
                    int d = dt * 16 + l15;
                    int c4 = ((kc * 4 + quad) ^ (d & 14));
                    half4 vf = *(const half4*)(vts + d * 64 + c4 * 4);
                    o[0][dt] = __builtin_amdgcn_mfma_f32_16x16x16f16(vf, pk[0][kc], o[0][dt], 0, 0, 0);
                    o[1][dt] = __builtin_amdgcn_mfma_f32_16x16x16f16(vf, pk[1][kc], o[1][dt], 0, 0, 0);
                }
        }

        __syncthreads();
        float* o1mb = (float*)&Ks[0][0][0];
        float* mlmb = (float*)&Vts[0][0][0];
        __hip_bfloat16* tb = (__hip_bfloat16*)((char*)&Vts[0][0][0] + 8192);
        if (grp == 1) {
            float* dst = o1mb + wl * 4096;
#pragma unroll
            for (int mt = 0; mt < 2; mt++)
#pragma unroll
                for (int dt = 0; dt < 8; dt++)
#pragma unroll
                    for (int r = 0; r < 4; r++)
                        dst[((mt * 8 + dt) * 4 + r) * 64 + lane] = o[mt][dt][r];
            float* ml = mlmb + (wl * 64 + lane) * 4;
            ml[0] = m_[0]; ml[1] = m_[1]; ml[2] = l_[0]; ml[3] = l_[1];
        }
        __syncthreads();
        if (grp == 0) {
            const float* src = o1mb + wl * 4096;
            const float* ml = mlmb + (wl * 64 + lane) * 4;
#pragma unroll
            for (int mt = 0; mt < 2; mt++) {
                float m1 = ml[mt], l1 = ml[2 + mt];
                float mm = fmaxf(m_[mt], m1);
                float a0 = __expf(m_[mt] - mm), a1 = __expf(m1 - mm);
                float linv = 1.0f / (l_[mt] * a0 + l1 * a1);
#pragma unroll
                for (int dt = 0; dt < 8; dt++)
#pragma unroll
                    for (int r = 0; r < 4; r++)
                        o[mt][dt][r] = (o[mt][dt][r] * a0 +
                                        src[((mt * 8 + dt) * 4 + r) * 64 + lane] * a1) * linv;
            }
            __hip_bfloat16* tw = tb + wl * 4096;
#pragma unroll
            for (int mt = 0; mt < 2; mt++)
#pragma unroll
                for (int dt = 0; dt < 8; dt++) {
                    int q32 = mt * 16 + l15;
                    int c4 = dt * 4 + quad;
                    int phys = c4 ^ ((q32 & 7) << 2);
                    union { unsigned short u[4]; uint2 dw; } pkb;
#pragma unroll
                    for (int r = 0; r < 4; r++) pkb.u[r] = f2bf(o[mt][dt][r]);
                    *(uint2*)(tw + q32 * 128 + phys * 4) = pkb.dw;
                }
#pragma unroll
            for (int pass = 0; pass < 8; pass++) {
                int q32 = pass * 4 + (lane >> 4);
                int p = l15;
                int phys = (p * 2) ^ ((q32 & 7) << 2);
                u32x4 val = *(const u32x4*)(tw + q32 * 128 + phys * 4);
                int qg = qt * 128 + wl * 32 + q32;
                *(u32x4*)(attn + (row0 + qg) * (size_t)DIM + h * HD + p * 8) = val;
            }
        }
        __syncthreads();
    }
}

extern "C" void kernel_launch(void* const* d_in, const int* in_sizes, int n_in,
                              void* d_out, int out_size, void* d_ws, size_t ws_size,
                              hipStream_t stream) {
    const float* x  = (const float*)d_in[0];
    const float* wq = (const float*)d_in[2];
    const float* wk = (const float*)d_in[3];
    const float* wv = (const float*)d_in[4];
    const float* wo = (const float*)d_in[5];
    float* out = (float*)d_out;

    char* ws = (char*)d_ws;
    __hip_bfloat16* xb    = (__hip_bfloat16*)(ws);                 // 4096x2048 (16MB)
    __hip_bfloat16* attn  = (__hip_bfloat16*)(ws);                 // reuses xb after QKV GEMM
    __hip_bfloat16* wqkvb = (__hip_bfloat16*)(ws + 16777216ull);   // 6144x2048 (24MB)
    __hip_bfloat16* wob   = (__hip_bfloat16*)(ws + 41943040ull);   // 2048x2048 (8MB)
    __hip_bfloat16* qkv   = (__hip_bfloat16*)(ws + 50331648ull);   // 4096x6144 (48MB; V cols unused)
    _Float16*       vtg   = (_Float16*)(ws + 100663296ull);        // 32x128x2048 f16 (16MB)

    const int nv = (BATCH * SEQ * DIM + 4 * DIM * DIM) / 4;
    cast_all<<<nv / 256, 256, 0, stream>>>(x, wq, wk, wv, wo, xb, wqkvb, wob);

    // QKV = xb @ wqkvb^T, 256x256 BK=32 ring kernel, fused RoPE (Q,K) + V-transpose
    gemm256_qkv<<<dim3(QKVN / 256, (BATCH * SEQ) / 256), 512, 0, stream>>>(
        xb, wqkvb, qkv, vtg);

    flash_kernel<<<dim3(8, BATCH * NH), 512, 0, stream>>>(qkv, vtg, attn);

    // out = attn @ wo^T : M=4096, N=2048, K=2048 (fp32 out)
    gemm_bt<0, float><<<dim3(DIM / 128, (BATCH * SEQ) / 128), 256, 0, stream>>>(
        attn, wob, out, nullptr, BATCH * SEQ, DIM, DIM);
}

// Round 6
// 404.441 us; speedup vs baseline: 1.0568x; 1.0568x over previous
//
#include <hip/hip_runtime.h>
#include <hip/hip_bf16.h>
#include <math.h>

#define DIM   2048
#define NH    16
#define HD    128
#define SEQ   2048
#define BATCH 2
#define QKVN  6144   // 3*DIM

typedef __attribute__((ext_vector_type(8))) short short8;
typedef __attribute__((ext_vector_type(4))) float f32x4;
typedef __attribute__((ext_vector_type(4))) unsigned int u32x4;
typedef __attribute__((ext_vector_type(4))) _Float16 half4;

static __device__ __forceinline__ unsigned short f2bf(float f) {
    __hip_bfloat16 h = __float2bfloat16(f);
    return *reinterpret_cast<unsigned short*>(&h);
}

// async global->LDS, 16B per lane; LDS dest = base + lane*16 (wave-uniform base)
static __device__ __forceinline__ void gload16(const void* g, void* l) {
    __builtin_amdgcn_global_load_lds(
        (const __attribute__((address_space(1))) void*)(g),
        (__attribute__((address_space(3))) void*)(l), 16, 0, 0);
}

__device__ __forceinline__ void storeC_helper(float* C, size_t idx, float v) { C[idx] = v; }
__device__ __forceinline__ void storeC_helper(__hip_bfloat16* C, size_t idx, float v) { C[idx] = __float2bfloat16(v); }

// ---------------- fused cast fp32 -> bf16 (x + 4 weights, one launch) ----------------
__global__ __launch_bounds__(256) void cast_all(const float* __restrict__ x,
                                                const float* __restrict__ wq,
                                                const float* __restrict__ wk,
                                                const float* __restrict__ wv,
                                                const float* __restrict__ wo,
                                                __hip_bfloat16* __restrict__ xb,
                                                __hip_bfloat16* __restrict__ wqkvb,
                                                __hip_bfloat16* __restrict__ wob) {
    const int VX = (BATCH * SEQ * DIM) / 4;
    const int VW = (DIM * DIM) / 4;
    int v = blockIdx.x * blockDim.x + threadIdx.x;
    const float* src; __hip_bfloat16* dst; int off;
    if (v < VX)               { src = x;  dst = xb;                            off = v; }
    else if (v < VX + VW)     { src = wq; dst = wqkvb;                         off = v - VX; }
    else if (v < VX + 2 * VW) { src = wk; dst = wqkvb + (size_t)DIM * DIM;     off = v - VX - VW; }
    else if (v < VX + 3 * VW) { src = wv; dst = wqkvb + 2ull * DIM * DIM;      off = v - VX - 2 * VW; }
    else                      { src = wo; dst = wob;                           off = v - VX - 3 * VW; }
    float4 f = *(const float4*)(src + (size_t)off * 4);
    union { unsigned short u[4]; uint2 d; } pk;
    pk.u[0] = f2bf(f.x); pk.u[1] = f2bf(f.y); pk.u[2] = f2bf(f.z); pk.u[3] = f2bf(f.w);
    *(uint2*)(dst + (size_t)off * 4) = pk.d;
}

// ---------------- bf16 GEMM, C[m,n] = sum_k A[m,k]*B[n,k] ----------------
// MODE 0: plain store to C.  MODE 1: QKV-fused — n<4096: RoPE + bf16 store;
// n>=4096: V tile transposed via LDS, stored f16 to vt[bh][d][s].
// T1: XCD-chunked block swizzle (nwg%8==0 for all launches) — each XCD gets a
// contiguous chunk of the work-linear space -> A/B panel reuse lands in its L2.
template <int MODE, typename OutT>
__global__ __launch_bounds__(256) void gemm_bt(const __hip_bfloat16* __restrict__ A,
                                               const __hip_bfloat16* __restrict__ B,
                                               OutT* __restrict__ C,
                                               _Float16* __restrict__ vt,
                                               int M, int N, int K) {
    constexpr int BK = 64;
    __shared__ __align__(16) __hip_bfloat16 As[128 * BK];
    __shared__ __align__(16) __hip_bfloat16 Bs[128 * BK];
    int tid  = threadIdx.x;
    int lane = tid & 63;
    int wave = tid >> 6;
    int quad = lane >> 4;
    int l15  = lane & 15;
    int wr   = wave >> 1, wc = wave & 1;

    // XCD-chunked swizzle: wgid%8 ~ XCD; give XCD k work chunk [k*q, (k+1)*q)
    int nwg  = gridDim.x * gridDim.y;
    int wgid = blockIdx.y * gridDim.x + blockIdx.x;
    int q8   = nwg >> 3;
    int swz  = (wgid & 7) * q8 + (wgid >> 3);
    int m0 = (swz / gridDim.x) * 128;
    int n0 = (swz % gridDim.x) * 128;
    f32x4 acc[4][4] = {};

    for (int k0 = 0; k0 < K; k0 += BK) {
        __syncthreads();
#pragma unroll
        for (int c = 0; c < 4; c++) {
            int br = (wave * 4 + c) * 8;
            int r  = br + (lane >> 3);
            int cc = (lane & 7) ^ (r & 7);
            gload16(A + (size_t)(m0 + r) * K + k0 + cc * 8, As + br * 64);
            gload16(B + (size_t)(n0 + r) * K + k0 + cc * 8, Bs + br * 64);
        }
        __syncthreads();
#pragma unroll
        for (int kk = 0; kk < BK; kk += 32) {
            short8 af[4], bf4[4];
#pragma unroll
            for (int t = 0; t < 4; t++) {
                int Ra = wr * 64 + t * 16 + l15;
                int pa = ((kk >> 3) + quad) ^ (Ra & 7);
                af[t] = *(const short8*)(As + Ra * 64 + pa * 8);
                int Rb = wc * 64 + t * 16 + l15;
                int pb = ((kk >> 3) + quad) ^ (Rb & 7);
                bf4[t] = *(const short8*)(Bs + Rb * 64 + pb * 8);
            }
#pragma unroll
            for (int mt = 0; mt < 4; mt++)
#pragma unroll
                for (int nt = 0; nt < 4; nt++)
                    acc[mt][nt] = __builtin_amdgcn_mfma_f32_16x16x32_bf16(af[mt], bf4[nt], acc[mt][nt], 0, 0, 0);
        }
    }

    if (MODE == 1 && n0 >= 4096) {
        // ---- V branch: transpose 64x64 wave quadrant via LDS, store f16 ----
        __syncthreads();   // all waves done reading As/Bs
        _Float16* T = ((wave < 2) ? (_Float16*)As : (_Float16*)Bs) + (wave & 1) * 4096;
#pragma unroll
        for (int mt = 0; mt < 4; mt++)
#pragma unroll
            for (int nt = 0; nt < 4; nt++) {
                int dcol = nt * 16 + l15;
#pragma unroll
                for (int r = 0; r < 4; r++) {
                    int row = mt * 16 + quad * 4 + r;   // s within quadrant
                    int chunk = (row >> 3) ^ (dcol & 7);
                    T[dcol * 64 + chunk * 8 + (row & 7)] = (_Float16)acc[mt][nt][r];
                }
            }
        int h = (n0 - 4096) >> 7;
        int b = m0 >> 11;
        int sbase = (m0 & (SEQ - 1)) + wr * 64;
#pragma unroll
        for (int pass = 0; pass < 8; pass++) {
            int dl = pass * 8 + (lane >> 3);
            int sc = lane & 7;
            int chunk = sc ^ (dl & 7);
            u32x4 val = *(const u32x4*)(T + dl * 64 + chunk * 8);
            int d = wc * 64 + dl;
            *(u32x4*)(vt + ((size_t)((b * NH + h) * HD + d)) * SEQ + sbase + sc * 8) = val;
        }
        return;
    }

#pragma unroll
    for (int nt = 0; nt < 4; nt++) {
        int col = n0 + wc * 64 + nt * 16 + l15;
        float theta = 0.f;
        if (MODE == 1)
            theta = __expf(-((float)((col & 127) & ~1) * (1.0f / (float)HD)) * 9.210340371976184f);
#pragma unroll
        for (int mt = 0; mt < 4; mt++)
#pragma unroll
            for (int r = 0; r < 4; r++) {
                int row = m0 + wr * 64 + mt * 16 + quad * 4 + r;
                float val = acc[mt][nt][r];
                if (MODE == 1) {
                    float part = __shfl_xor(val, 1);
                    int s = row & (SEQ - 1);
                    float sn, cs;
                    __sincosf((float)s * theta, &sn, &cs);
                    val = (l15 & 1) ? val * cs + part * sn : val * cs - part * sn;
                }
                storeC_helper(C, (size_t)row * N + col, val);
            }
    }
}

// ---------------- flash attention (causal) ----------------
// 512 threads = 8 waves = 2 groups x 4. qtile=128 (wave owns 32 q-rows).
// Group g processes half the key range; online-softmax partials merged in LDS.
// Pairs (i,15-i): every block 17+17 iters. grid (8,32)=256 blocks, 2 waves/SIMD.
// S^T = K·Q^T so P exits in B-operand layout for 16x16x16 f16 PV.
// T1: XCD-chunked swizzle so each XCD owns 4 whole heads -> K/V stay L2-resident.
__global__ __launch_bounds__(512, 2) void flash_kernel(const __hip_bfloat16* __restrict__ qkv,
                                                       const _Float16* __restrict__ vt,
                                                       __hip_bfloat16* __restrict__ attn) {
    __shared__ __align__(16) __hip_bfloat16 Ks[2][2][64 * 128];   // [group][buf] 64KB
    __shared__ __align__(16) _Float16 Vts[2][2][128 * 64];        // [group][buf] 64KB
    int tid  = threadIdx.x;
    int lane = tid & 63;
    int wave = tid >> 6;
    int grp  = wave >> 2;
    int wl   = wave & 3;
    int quad = lane >> 4;
    int l15  = lane & 15;
    // XCD-chunked swizzle: nwg=256, q=32 -> XCD k gets work 32k..32k+31 = 4 heads
    int wgid = blockIdx.y * 8 + blockIdx.x;
    int swz  = (wgid & 7) * 32 + (wgid >> 3);
    int pairi = swz & 7;
    int bh = swz >> 3;
    int b  = bh >> 4;
    int h  = bh & 15;
    size_t row0 = (size_t)b * SEQ;
    const _Float16* vbase = vt + (size_t)bh * HD * SEQ;
    const float scale = 0.08838834764831845f;
    const float NEG = -1e30f;

    auto stage = [&](int buf, int kt) {
#pragma unroll
        for (int c = 0; c < 4; c++) {
            int br = (wl * 4 + c) * 4;
            int r  = br + (lane >> 4);
            int cc = (lane & 15) ^ (r & 15);
            gload16(qkv + (row0 + kt * 64 + r) * (size_t)QKVN + DIM + h * HD + cc * 8,
                    &Ks[grp][buf][br * 128]);
        }
#pragma unroll
        for (int c = 0; c < 4; c++) {
            int br = (wl * 4 + c) * 8;
            int r  = br + (lane >> 3);
            int cc = (lane & 7) ^ ((r >> 1) & 7);
            gload16(vbase + (size_t)r * SEQ + kt * 64 + cc * 8, &Vts[grp][buf][br * 64]);
        }
    };

    for (int seg = 0; seg < 2; seg++) {
        int qt = seg ? (15 - pairi) : pairi;
        int half = qt + 1;
        int kbase = grp ? half : 0;

        short8 qf[2][4];
#pragma unroll
        for (int mt = 0; mt < 2; mt++) {
            int qrow = qt * 128 + wl * 32 + mt * 16 + l15;
            const __hip_bfloat16* qptr = qkv + (row0 + qrow) * (size_t)QKVN + h * HD + quad * 8;
#pragma unroll
            for (int c = 0; c < 4; c++) qf[mt][c] = *(const short8*)(qptr + c * 32);
        }
        f32x4 o[2][8] = {};
        float m_[2] = {NEG, NEG}, l_[2] = {0.f, 0.f};

        stage(0, kbase);

        for (int i = 0; i < half; i++) {
            __syncthreads();
            if (i + 1 < half) stage((i + 1) & 1, kbase + i + 1);
            int kt = kbase + i;
            const __hip_bfloat16* ks = Ks[grp][i & 1];
            const _Float16* vts = Vts[grp][i & 1];

            f32x4 s[2][4] = {};
#pragma unroll
            for (int ktile = 0; ktile < 4; ktile++) {
                int R = ktile * 16 + l15;
#pragma unroll
                for (int c = 0; c < 4; c++) {
                    int phys = (c * 4 + quad) ^ (R & 15);
                    short8 kf = *(const short8*)(ks + R * 128 + phys * 8);
                    s[0][ktile] = __builtin_amdgcn_mfma_f32_16x16x32_bf16(kf, qf[0][c], s[0][ktile], 0, 0, 0);
                    s[1][ktile] = __builtin_amdgcn_mfma_f32_16x16x32_bf16(kf, qf[1][c], s[1][ktile], 0, 0, 0);
                }
            }
            bool diag = (kt >= 2 * qt);
            float alpha[2];
#pragma unroll
            for (int mt = 0; mt < 2; mt++) {
                int q = qt * 128 + wl * 32 + mt * 16 + l15;
#pragma unroll
                for (int ktile = 0; ktile < 4; ktile++)
#pragma unroll
                    for (int r = 0; r < 4; r++) {
                        float v = s[mt][ktile][r] * scale;
                        if (diag) {
                            int key = kt * 64 + ktile * 16 + quad * 4 + r;
                            if (key > q) v = NEG;
                        }
                        s[mt][ktile][r] = v;
                    }
                float v = s[mt][0][0];
#pragma unroll
                for (int ktile = 0; ktile < 4; ktile++)
#pragma unroll
                    for (int r = 0; r < 4; r++) v = fmaxf(v, s[mt][ktile][r]);
                v = fmaxf(v, __shfl_xor(v, 16));
                v = fmaxf(v, __shfl_xor(v, 32));
                float mnew = fmaxf(m_[mt], v);
                alpha[mt] = __expf(m_[mt] - mnew);
                m_[mt] = mnew;
                float sum = 0.f;
#pragma unroll
                for (int ktile = 0; ktile < 4; ktile++)
#pragma unroll
                    for (int r = 0; r < 4; r++) {
                        float p = __expf(s[mt][ktile][r] - mnew);
                        s[mt][ktile][r] = p;
                        sum += p;
                    }
                sum += __shfl_xor(sum, 16);
                sum += __shfl_xor(sum, 32);
                l_[mt] = l_[mt] * alpha[mt] + sum;
#pragma unroll
                for (int dt = 0; dt < 8; dt++) o[mt][dt] *= alpha[mt];
            }
            half4 pk[2][4];
#pragma unroll
            for (int mt = 0; mt < 2; mt++)
#pragma unroll
                for (int kc = 0; kc < 4; kc++)
#pragma unroll
                    for (int r = 0; r < 4; r++) pk[mt][kc][r] = (_Float16)s[mt][kc][r];
#pragma unroll
            for (int kc = 0; kc < 4; kc++)
#pragma unroll
                for (int dt = 0; dt < 8; dt++) {
                    int d = dt * 16 + l15;
                    int c4 = ((kc * 4 + quad) ^ (d & 14));
                    half4 vf = *(const half4*)(vts + d * 64 + c4 * 4);
                    o[0][dt] = __builtin_amdgcn_mfma_f32_16x16x16f16(vf, pk[0][kc], o[0][dt], 0, 0, 0);
                    o[1][dt] = __builtin_amdgcn_mfma_f32_16x16x16f16(vf, pk[1][kc], o[1][dt], 0, 0, 0);
                }
        }

        __syncthreads();
        float* o1mb = (float*)&Ks[0][0][0];
        float* mlmb = (float*)&Vts[0][0][0];
        __hip_bfloat16* tb = (__hip_bfloat16*)((char*)&Vts[0][0][0] + 8192);
        if (grp == 1) {
            float* dst = o1mb + wl * 4096;
#pragma unroll
            for (int mt = 0; mt < 2; mt++)
#pragma unroll
                for (int dt = 0; dt < 8; dt++)
#pragma unroll
                    for (int r = 0; r < 4; r++)
                        dst[((mt * 8 + dt) * 4 + r) * 64 + lane] = o[mt][dt][r];
            float* ml = mlmb + (wl * 64 + lane) * 4;
            ml[0] = m_[0]; ml[1] = m_[1]; ml[2] = l_[0]; ml[3] = l_[1];
        }
        __syncthreads();
        if (grp == 0) {
            const float* src = o1mb + wl * 4096;
            const float* ml = mlmb + (wl * 64 + lane) * 4;
#pragma unroll
            for (int mt = 0; mt < 2; mt++) {
                float m1 = ml[mt], l1 = ml[2 + mt];
                float mm = fmaxf(m_[mt], m1);
                float a0 = __expf(m_[mt] - mm), a1 = __expf(m1 - mm);
                float linv = 1.0f / (l_[mt] * a0 + l1 * a1);
#pragma unroll
                for (int dt = 0; dt < 8; dt++)
#pragma unroll
                    for (int r = 0; r < 4; r++)
                        o[mt][dt][r] = (o[mt][dt][r] * a0 +
                                        src[((mt * 8 + dt) * 4 + r) * 64 + lane] * a1) * linv;
            }
            __hip_bfloat16* tw = tb + wl * 4096;
#pragma unroll
            for (int mt = 0; mt < 2; mt++)
#pragma unroll
                for (int dt = 0; dt < 8; dt++) {
                    int q32 = mt * 16 + l15;
                    int c4 = dt * 4 + quad;
                    int phys = c4 ^ ((q32 & 7) << 2);
                    union { unsigned short u[4]; uint2 dw; } pkb;
#pragma unroll
                    for (int r = 0; r < 4; r++) pkb.u[r] = f2bf(o[mt][dt][r]);
                    *(uint2*)(tw + q32 * 128 + phys * 4) = pkb.dw;
                }
#pragma unroll
            for (int pass = 0; pass < 8; pass++) {
                int q32 = pass * 4 + (lane >> 4);
                int p = l15;
                int phys = (p * 2) ^ ((q32 & 7) << 2);
                u32x4 val = *(const u32x4*)(tw + q32 * 128 + phys * 4);
                int qg = qt * 128 + wl * 32 + q32;
                *(u32x4*)(attn + (row0 + qg) * (size_t)DIM + h * HD + p * 8) = val;
            }
        }
        __syncthreads();
    }
}

extern "C" void kernel_launch(void* const* d_in, const int* in_sizes, int n_in,
                              void* d_out, int out_size, void* d_ws, size_t ws_size,
                              hipStream_t stream) {
    const float* x  = (const float*)d_in[0];
    const float* wq = (const float*)d_in[2];
    const float* wk = (const float*)d_in[3];
    const float* wv = (const float*)d_in[4];
    const float* wo = (const float*)d_in[5];
    float* out = (float*)d_out;

    char* ws = (char*)d_ws;
    __hip_bfloat16* xb    = (__hip_bfloat16*)(ws);                 // 4096x2048 (16MB)
    __hip_bfloat16* attn  = (__hip_bfloat16*)(ws);                 // reuses xb after QKV GEMM
    __hip_bfloat16* wqkvb = (__hip_bfloat16*)(ws + 16777216ull);   // 6144x2048 (24MB)
    __hip_bfloat16* wob   = (__hip_bfloat16*)(ws + 41943040ull);   // 2048x2048 (8MB)
    __hip_bfloat16* qkv   = (__hip_bfloat16*)(ws + 50331648ull);   // 4096x6144 (48MB; V cols unused)
    _Float16*       vtg   = (_Float16*)(ws + 100663296ull);        // 32x128x2048 f16 (16MB)

    const int nv = (BATCH * SEQ * DIM + 4 * DIM * DIM) / 4;
    cast_all<<<nv / 256, 256, 0, stream>>>(x, wq, wk, wv, wo, xb, wqkvb, wob);

    // QKV = xb @ wqkvb^T with fused RoPE (Q,K) + V-transpose epilogue (proven 128²)
    gemm_bt<1, __hip_bfloat16><<<dim3(QKVN / 128, (BATCH * SEQ) / 128), 256, 0, stream>>>(
        xb, wqkvb, qkv, vtg, BATCH * SEQ, QKVN, DIM);

    flash_kernel<<<dim3(8, BATCH * NH), 512, 0, stream>>>(qkv, vtg, attn);

    // out = attn @ wo^T : M=4096, N=2048, K=2048 (fp32 out)
    gemm_bt<0, float><<<dim3(DIM / 128, (BATCH * SEQ) / 128), 256, 0, stream>>>(
        attn, wob, out, nullptr, BATCH * SEQ, DIM, DIM);
}

// Round 8
// 403.371 us; speedup vs baseline: 1.0596x; 1.0027x over previous
//
#include <hip/hip_runtime.h>
#include <hip/hip_bf16.h>
#include <math.h>

#define DIM   2048
#define NH    16
#define HD    128
#define SEQ   2048
#define BATCH 2
#define QKVN  6144   // 3*DIM

typedef __attribute__((ext_vector_type(8))) short short8;
typedef __attribute__((ext_vector_type(4))) float f32x4;
typedef __attribute__((ext_vector_type(4))) unsigned int u32x4;
typedef __attribute__((ext_vector_type(4))) _Float16 half4;

static __device__ __forceinline__ unsigned short f2bf(float f) {
    __hip_bfloat16 h = __float2bfloat16(f);
    return *reinterpret_cast<unsigned short*>(&h);
}

// async global->LDS, 16B per lane; LDS dest = base + lane*16 (wave-uniform base)
static __device__ __forceinline__ void gload16(const void* g, void* l) {
    __builtin_amdgcn_global_load_lds(
        (const __attribute__((address_space(1))) void*)(g),
        (__attribute__((address_space(3))) void*)(l), 16, 0, 0);
}

__device__ __forceinline__ void storeC_helper(float* C, size_t idx, float v) { C[idx] = v; }
__device__ __forceinline__ void storeC_helper(__hip_bfloat16* C, size_t idx, float v) { C[idx] = __float2bfloat16(v); }

// ---------------- fused cast fp32 -> bf16 (x + 4 weights, one launch) ----------------
__global__ __launch_bounds__(256) void cast_all(const float* __restrict__ x,
                                                const float* __restrict__ wq,
                                                const float* __restrict__ wk,
                                                const float* __restrict__ wv,
                                                const float* __restrict__ wo,
                                                __hip_bfloat16* __restrict__ xb,
                                                __hip_bfloat16* __restrict__ wqkvb,
                                                __hip_bfloat16* __restrict__ wob) {
    const int VX = (BATCH * SEQ * DIM) / 4;
    const int VW = (DIM * DIM) / 4;
    int v = blockIdx.x * blockDim.x + threadIdx.x;
    const float* src; __hip_bfloat16* dst; int off;
    if (v < VX)               { src = x;  dst = xb;                            off = v; }
    else if (v < VX + VW)     { src = wq; dst = wqkvb;                         off = v - VX; }
    else if (v < VX + 2 * VW) { src = wk; dst = wqkvb + (size_t)DIM * DIM;     off = v - VX - VW; }
    else if (v < VX + 3 * VW) { src = wv; dst = wqkvb + 2ull * DIM * DIM;      off = v - VX - 2 * VW; }
    else                      { src = wo; dst = wob;                           off = v - VX - 3 * VW; }
    float4 f = *(const float4*)(src + (size_t)off * 4);
    union { unsigned short u[4]; uint2 d; } pk;
    pk.u[0] = f2bf(f.x); pk.u[1] = f2bf(f.y); pk.u[2] = f2bf(f.z); pk.u[3] = f2bf(f.w);
    *(uint2*)(dst + (size_t)off * 4) = pk.d;
}

// ---------------- bf16 GEMM, C[m,n] = sum_k A[m,k]*B[n,k] ----------------
// MODE 0: plain store to C.  MODE 1: QKV-fused — n<4096: RoPE + bf16 store;
// n>=4096: V tile transposed via LDS, stored f16 to vt[bh][d][s].
// NOTE r6: XCD-chunked swizzle REVERTED — it gave each XCD all 48 B-panels
// (25MB through a 4MB L2): FETCH 107->330MB. Default round-robin is better here.
template <int MODE, typename OutT>
__global__ __launch_bounds__(256) void gemm_bt(const __hip_bfloat16* __restrict__ A,
                                               const __hip_bfloat16* __restrict__ B,
                                               OutT* __restrict__ C,
                                               _Float16* __restrict__ vt,
                                               int M, int N, int K) {
    constexpr int BK = 64;
    __shared__ __align__(16) __hip_bfloat16 As[128 * BK];
    __shared__ __align__(16) __hip_bfloat16 Bs[128 * BK];
    int tid  = threadIdx.x;
    int lane = tid & 63;
    int wave = tid >> 6;
    int quad = lane >> 4;
    int l15  = lane & 15;
    int wr   = wave >> 1, wc = wave & 1;
    int m0 = blockIdx.y * 128;
    int n0 = blockIdx.x * 128;
    f32x4 acc[4][4] = {};

    for (int k0 = 0; k0 < K; k0 += BK) {
        __syncthreads();
#pragma unroll
        for (int c = 0; c < 4; c++) {
            int br = (wave * 4 + c) * 8;
            int r  = br + (lane >> 3);
            int cc = (lane & 7) ^ (r & 7);
            gload16(A + (size_t)(m0 + r) * K + k0 + cc * 8, As + br * 64);
            gload16(B + (size_t)(n0 + r) * K + k0 + cc * 8, Bs + br * 64);
        }
        __syncthreads();
#pragma unroll
        for (int kk = 0; kk < BK; kk += 32) {
            short8 af[4], bf4[4];
#pragma unroll
            for (int t = 0; t < 4; t++) {
                int Ra = wr * 64 + t * 16 + l15;
                int pa = ((kk >> 3) + quad) ^ (Ra & 7);
                af[t] = *(const short8*)(As + Ra * 64 + pa * 8);
                int Rb = wc * 64 + t * 16 + l15;
                int pb = ((kk >> 3) + quad) ^ (Rb & 7);
                bf4[t] = *(const short8*)(Bs + Rb * 64 + pb * 8);
            }
#pragma unroll
            for (int mt = 0; mt < 4; mt++)
#pragma unroll
                for (int nt = 0; nt < 4; nt++)
                    acc[mt][nt] = __builtin_amdgcn_mfma_f32_16x16x32_bf16(af[mt], bf4[nt], acc[mt][nt], 0, 0, 0);
        }
    }

    if (MODE == 1 && n0 >= 4096) {
        // ---- V branch: transpose 64x64 wave quadrant via LDS, store f16 ----
        __syncthreads();   // all waves done reading As/Bs
        _Float16* T = ((wave < 2) ? (_Float16*)As : (_Float16*)Bs) + (wave & 1) * 4096;
#pragma unroll
        for (int mt = 0; mt < 4; mt++)
#pragma unroll
            for (int nt = 0; nt < 4; nt++) {
                int dcol = nt * 16 + l15;
#pragma unroll
                for (int r = 0; r < 4; r++) {
                    int row = mt * 16 + quad * 4 + r;   // s within quadrant
                    int chunk = (row >> 3) ^ (dcol & 7);
                    T[dcol * 64 + chunk * 8 + (row & 7)] = (_Float16)acc[mt][nt][r];
                }
            }
        int h = (n0 - 4096) >> 7;
        int b = m0 >> 11;
        int sbase = (m0 & (SEQ - 1)) + wr * 64;
#pragma unroll
        for (int pass = 0; pass < 8; pass++) {
            int dl = pass * 8 + (lane >> 3);
            int sc = lane & 7;
            int chunk = sc ^ (dl & 7);
            u32x4 val = *(const u32x4*)(T + dl * 64 + chunk * 8);
            int d = wc * 64 + dl;
            *(u32x4*)(vt + ((size_t)((b * NH + h) * HD + d)) * SEQ + sbase + sc * 8) = val;
        }
        return;
    }

#pragma unroll
    for (int nt = 0; nt < 4; nt++) {
        int col = n0 + wc * 64 + nt * 16 + l15;
        float theta = 0.f;
        if (MODE == 1)
            theta = __expf(-((float)((col & 127) & ~1) * (1.0f / (float)HD)) * 9.210340371976184f);
#pragma unroll
        for (int mt = 0; mt < 4; mt++)
#pragma unroll
            for (int r = 0; r < 4; r++) {
                int row = m0 + wr * 64 + mt * 16 + quad * 4 + r;
                float val = acc[mt][nt][r];
                if (MODE == 1) {
                    float part = __shfl_xor(val, 1);
                    int s = row & (SEQ - 1);
                    float sn, cs;
                    __sincosf((float)s * theta, &sn, &cs);
                    val = (l15 & 1) ? val * cs + part * sn : val * cs - part * sn;
                }
                storeC_helper(C, (size_t)row * N + col, val);
            }
    }
}

// ---------------- flash attention (causal) ----------------
// 512 threads = 8 waves = 2 groups x 4. qtile=128 (wave owns 32 q-rows).
// Group g processes half the key range; online-softmax partials merged in LDS.
// Pairs (i,15-i): every block 17+17 iters. grid (8,32)=256 blocks, 2 waves/SIMD.
// S^T = K·Q^T so P exits in B-operand layout for 16x16x16 f16 PV.
// r6 additions: T5 setprio around MFMA clusters; T13 defer-max (THR=8) skips
// the O-rescale when the tile max doesn't raise the running max by >8
// (P <= e^8 ~ 2981, fits f16/f32 accum; first tile always rescales).
__global__ __launch_bounds__(512, 2) void flash_kernel(const __hip_bfloat16* __restrict__ qkv,
                                                       const _Float16* __restrict__ vt,
                                                       __hip_bfloat16* __restrict__ attn) {
    __shared__ __align__(16) __hip_bfloat16 Ks[2][2][64 * 128];   // [group][buf] 64KB
    __shared__ __align__(16) _Float16 Vts[2][2][128 * 64];        // [group][buf] 64KB
    int tid  = threadIdx.x;
    int lane = tid & 63;
    int wave = tid >> 6;
    int grp  = wave >> 2;
    int wl   = wave & 3;
    int quad = lane >> 4;
    int l15  = lane & 15;
    int pairi = blockIdx.x;
    int bh = blockIdx.y;
    int b  = bh >> 4;
    int h  = bh & 15;
    size_t row0 = (size_t)b * SEQ;
    const _Float16* vbase = vt + (size_t)bh * HD * SEQ;
    const float scale = 0.08838834764831845f;
    const float NEG = -1e30f;

    auto stage = [&](int buf, int kt) {
#pragma unroll
        for (int c = 0; c < 4; c++) {
            int br = (wl * 4 + c) * 4;
            int r  = br + (lane >> 4);
            int cc = (lane & 15) ^ (r & 15);
            gload16(qkv + (row0 + kt * 64 + r) * (size_t)QKVN + DIM + h * HD + cc * 8,
                    &Ks[grp][buf][br * 128]);
        }
#pragma unroll
        for (int c = 0; c < 4; c++) {
            int br = (wl * 4 + c) * 8;
            int r  = br + (lane >> 3);
            int cc = (lane & 7) ^ ((r >> 1) & 7);
            gload16(vbase + (size_t)r * SEQ + kt * 64 + cc * 8, &Vts[grp][buf][br * 64]);
        }
    };

    for (int seg = 0; seg < 2; seg++) {
        int qt = seg ? (15 - pairi) : pairi;
        int half = qt + 1;
        int kbase = grp ? half : 0;

        short8 qf[2][4];
#pragma unroll
        for (int mt = 0; mt < 2; mt++) {
            int qrow = qt * 128 + wl * 32 + mt * 16 + l15;
            const __hip_bfloat16* qptr = qkv + (row0 + qrow) * (size_t)QKVN + h * HD + quad * 8;
#pragma unroll
            for (int c = 0; c < 4; c++) qf[mt][c] = *(const short8*)(qptr + c * 32);
        }
        f32x4 o[2][8] = {};
        float m_[2] = {NEG, NEG}, l_[2] = {0.f, 0.f};

        stage(0, kbase);

        for (int i = 0; i < half; i++) {
            __syncthreads();
            if (i + 1 < half) stage((i + 1) & 1, kbase + i + 1);
            int kt = kbase + i;
            const __hip_bfloat16* ks = Ks[grp][i & 1];
            const _Float16* vts = Vts[grp][i & 1];

            f32x4 s[2][4] = {};
            __builtin_amdgcn_s_setprio(1);
#pragma unroll
            for (int ktile = 0; ktile < 4; ktile++) {
                int R = ktile * 16 + l15;
#pragma unroll
                for (int c = 0; c < 4; c++) {
                    int phys = (c * 4 + quad) ^ (R & 15);
                    short8 kf = *(const short8*)(ks + R * 128 + phys * 8);
                    s[0][ktile] = __builtin_amdgcn_mfma_f32_16x16x32_bf16(kf, qf[0][c], s[0][ktile], 0, 0, 0);
                    s[1][ktile] = __builtin_amdgcn_mfma_f32_16x16x32_bf16(kf, qf[1][c], s[1][ktile], 0, 0, 0);
                }
            }
            __builtin_amdgcn_s_setprio(0);
            bool diag = (kt >= 2 * qt);
#pragma unroll
            for (int mt = 0; mt < 2; mt++) {
                int q = qt * 128 + wl * 32 + mt * 16 + l15;
#pragma unroll
                for (int ktile = 0; ktile < 4; ktile++)
#pragma unroll
                    for (int r = 0; r < 4; r++) {
                        float v = s[mt][ktile][r] * scale;
                        if (diag) {
                            int key = kt * 64 + ktile * 16 + quad * 4 + r;
                            if (key > q) v = NEG;
                        }
                        s[mt][ktile][r] = v;
                    }
                float v = s[mt][0][0];
#pragma unroll
                for (int ktile = 0; ktile < 4; ktile++)
#pragma unroll
                    for (int r = 0; r < 4; r++) v = fmaxf(v, s[mt][ktile][r]);
                v = fmaxf(v, __shfl_xor(v, 16));
                v = fmaxf(v, __shfl_xor(v, 32));
                // T13 defer-max: only rescale when tile max exceeds running max + 8
                if (!__all(v - m_[mt] <= 8.0f)) {
                    float mnew = fmaxf(m_[mt], v);
                    float alpha = __expf(m_[mt] - mnew);
                    m_[mt] = mnew;
                    l_[mt] *= alpha;
#pragma unroll
                    for (int dt = 0; dt < 8; dt++) o[mt][dt] *= alpha;
                }
                float mref = m_[mt];
                float sum = 0.f;
#pragma unroll
                for (int ktile = 0; ktile < 4; ktile++)
#pragma unroll
                    for (int r = 0; r < 4; r++) {
                        float p = __expf(s[mt][ktile][r] - mref);
                        s[mt][ktile][r] = p;
                        sum += p;
                    }
                sum += __shfl_xor(sum, 16);
                sum += __shfl_xor(sum, 32);
                l_[mt] += sum;
            }
            half4 pk[2][4];
#pragma unroll
            for (int mt = 0; mt < 2; mt++)
#pragma unroll
                for (int kc = 0; kc < 4; kc++)
#pragma unroll
                    for (int r = 0; r < 4; r++) pk[mt][kc][r] = (_Float16)s[mt][kc][r];
            __builtin_amdgcn_s_setprio(1);
#pragma unroll
            for (int kc = 0; kc < 4; kc++)
#pragma unroll
                for (int dt = 0; dt < 8; dt++) {
                    int d = dt * 16 + l15;
                    int c4 = ((kc * 4 + quad) ^ (d & 14));
                    half4 vf = *(const half4*)(vts + d * 64 + c4 * 4);
                    o[0][dt] = __builtin_amdgcn_mfma_f32_16x16x16f16(vf, pk[0][kc], o[0][dt], 0, 0, 0);
                    o[1][dt] = __builtin_amdgcn_mfma_f32_16x16x16f16(vf, pk[1][kc], o[1][dt], 0, 0, 0);
                }
            __builtin_amdgcn_s_setprio(0);
        }

        __syncthreads();
        float* o1mb = (float*)&Ks[0][0][0];
        float* mlmb = (float*)&Vts[0][0][0];
        __hip_bfloat16* tb = (__hip_bfloat16*)((char*)&Vts[0][0][0] + 8192);
        if (grp == 1) {
            float* dst = o1mb + wl * 4096;
#pragma unroll
            for (int mt = 0; mt < 2; mt++)
#pragma unroll
                for (int dt = 0; dt < 8; dt++)
#pragma unroll
                    for (int r = 0; r < 4; r++)
                        dst[((mt * 8 + dt) * 4 + r) * 64 + lane] = o[mt][dt][r];
            float* ml = mlmb + (wl * 64 + lane) * 4;
            ml[0] = m_[0]; ml[1] = m_[1]; ml[2] = l_[0]; ml[3] = l_[1];
        }
        __syncthreads();
        if (grp == 0) {
            const float* src = o1mb + wl * 4096;
            const float* ml = mlmb + (wl * 64 + lane) * 4;
#pragma unroll
            for (int mt = 0; mt < 2; mt++) {
                float m1 = ml[mt], l1 = ml[2 + mt];
                float mm = fmaxf(m_[mt], m1);
                float a0 = __expf(m_[mt] - mm), a1 = __expf(m1 - mm);
                float linv = 1.0f / (l_[mt] * a0 + l1 * a1);
#pragma unroll
                for (int dt = 0; dt < 8; dt++)
#pragma unroll
                    for (int r = 0; r < 4; r++)
                        o[mt][dt][r] = (o[mt][dt][r] * a0 +
                                        src[((mt * 8 + dt) * 4 + r) * 64 + lane] * a1) * linv;
            }
            __hip_bfloat16* tw = tb + wl * 4096;
#pragma unroll
            for (int mt = 0; mt < 2; mt++)
#pragma unroll
                for (int dt = 0; dt < 8; dt++) {
                    int q32 = mt * 16 + l15;
                    int c4 = dt * 4 + quad;
                    int phys = c4 ^ ((q32 & 7) << 2);
                    union { unsigned short u[4]; uint2 dw; } pkb;
#pragma unroll
                    for (int r = 0; r < 4; r++) pkb.u[r] = f2bf(o[mt][dt][r]);
                    *(uint2*)(tw + q32 * 128 + phys * 4) = pkb.dw;
                }
#pragma unroll
            for (int pass = 0; pass < 8; pass++) {
                int q32 = pass * 4 + (lane >> 4);
                int p = l15;
                int phys = (p * 2) ^ ((q32 & 7) << 2);
                u32x4 val = *(const u32x4*)(tw + q32 * 128 + phys * 4);
                int qg = qt * 128 + wl * 32 + q32;
                *(u32x4*)(attn + (row0 + qg) * (size_t)DIM + h * HD + p * 8) = val;
            }
        }
        __syncthreads();
    }
}

extern "C" void kernel_launch(void* const* d_in, const int* in_sizes, int n_in,
                              void* d_out, int out_size, void* d_ws, size_t ws_size,
                              hipStream_t stream) {
    const float* x  = (const float*)d_in[0];
    const float* wq = (const float*)d_in[2];
    const float* wk = (const float*)d_in[3];
    const float* wv = (const float*)d_in[4];
    const float* wo = (const float*)d_in[5];
    float* out = (float*)d_out;

    char* ws = (char*)d_ws;
    __hip_bfloat16* xb    = (__hip_bfloat16*)(ws);                 // 4096x2048 (16MB)
    __hip_bfloat16* attn  = (__hip_bfloat16*)(ws);                 // reuses xb after QKV GEMM
    __hip_bfloat16* wqkvb = (__hip_bfloat16*)(ws + 16777216ull);   // 6144x2048 (24MB)
    __hip_bfloat16* wob   = (__hip_bfloat16*)(ws + 41943040ull);   // 2048x2048 (8MB)
    __hip_bfloat16* qkv   = (__hip_bfloat16*)(ws + 50331648ull);   // 4096x6144 (48MB; V cols unused)
    _Float16*       vtg   = (_Float16*)(ws + 100663296ull);        // 32x128x2048 f16 (16MB)

    const int nv = (BATCH * SEQ * DIM + 4 * DIM * DIM) / 4;
    cast_all<<<nv / 256, 256, 0, stream>>>(x, wq, wk, wv, wo, xb, wqkvb, wob);

    // QKV = xb @ wqkvb^T with fused RoPE (Q,K) + V-transpose epilogue
    gemm_bt<1, __hip_bfloat16><<<dim3(QKVN / 128, (BATCH * SEQ) / 128), 256, 0, stream>>>(
        xb, wqkvb, qkv, vtg, BATCH * SEQ, QKVN, DIM);

    flash_kernel<<<dim3(8, BATCH * NH), 512, 0, stream>>>(qkv, vtg, attn);

    // out = attn @ wo^T : M=4096, N=2048, K=2048 (fp32 out)
    gemm_bt<0, float><<<dim3(DIM / 128, (BATCH * SEQ) / 128), 256, 0, stream>>>(
        attn, wob, out, nullptr, BATCH * SEQ, DIM, DIM);
}